// Round 3
// baseline (241.241 us; speedup 1.0000x reference)
//
#include <hip/hip_runtime.h>

// InvRT: out[m,n,b,l] = -(e0 + e1*tanh((z - e2)*e3)), params from eta_fault[Mask[m,l]]
// z (8,64,512,128) f32. HBM-bound streaming op; floor ~35-43us.
// R1/R2: depth-4 software pipeline (4 float4 loads in flight/wave) + relaxed
// launch_bounds (R0's 24 VGPRs -> 1 load in flight -> latency-bound, 82us).
// R2 fix: __builtin_nontemporal_store needs a native vector type, not HIP's
// float4 struct -> use ext_vector_type(4) float throughout.

#define M_DIM 8
#define L_DIM 128
#define PER_M 4194304       // N*B*L floats per m
#define BLOCKS_PER_M 256
#define THREADS 256
#define PER_BLOCK 16384     // PER_M / BLOCKS_PER_M
#define ITERS 16            // float4s per thread
#define STRIDE (THREADS * 4)

typedef float f32x4 __attribute__((ext_vector_type(4)));

__device__ __forceinline__ float fast_tanh(float x) {
    // tanh(x) = 1 - 2/(1 + exp2(x * 2*log2e)); saturates correctly at +-1.
    float t = __builtin_amdgcn_exp2f(x * 2.8853900817779268f);
    float r = __builtin_amdgcn_rcpf(1.0f + t);
    return __builtin_fmaf(-2.0f, r, 1.0f);
}

__global__ __launch_bounds__(THREADS, 1) void invrt_kernel(
    const float* __restrict__ z,
    const float* __restrict__ eta_fault,
    const int*  __restrict__ mask,
    float* __restrict__ out)
{
    const int tid   = threadIdx.x;
    const int bid   = blockIdx.x;
    const int m     = bid >> 8;       // 256 blocks per m
    const int chunk = bid & 255;

    // Thread owns l = l0..l0+3 for every iteration (block stride 1024 is a
    // multiple of L=128, so the l-phase is loop-invariant).
    const int l0 = (tid & 31) * 4;

    float a0[4], a1[4], a2[4], a3[4];
#pragma unroll
    for (int j = 0; j < 4; ++j) {
        const int row = mask[m * L_DIM + l0 + j];     // 0..18
        const f32x4 e = *reinterpret_cast<const f32x4*>(eta_fault + row * 4);
        a0[j] = -e.x;   // -e0
        a1[j] = -e.y;   // -e1
        a2[j] = e.z;    //  e2
        a3[j] = e.w;    //  e3
    }

    const long long base = (long long)m * PER_M + (long long)chunk * PER_BLOCK + tid * 4;
    const float* zp = z + base;
    float*       op = out + base;

#define LDZ(i) (*reinterpret_cast<const f32x4*>(zp + (i) * STRIDE))

    f32x4 cur[4], nxt[4];
#pragma unroll
    for (int j = 0; j < 4; ++j) cur[j] = LDZ(j);

#pragma unroll
    for (int g = 1; g <= ITERS / 4; ++g) {
        if (g < ITERS / 4) {
#pragma unroll
            for (int j = 0; j < 4; ++j) nxt[j] = LDZ(g * 4 + j);
        }
#pragma unroll
        for (int j = 0; j < 4; ++j) {
            const f32x4 v = cur[j];
            f32x4 o;
            o.x = __builtin_fmaf(a1[0], fast_tanh((v.x - a2[0]) * a3[0]), a0[0]);
            o.y = __builtin_fmaf(a1[1], fast_tanh((v.y - a2[1]) * a3[1]), a0[1]);
            o.z = __builtin_fmaf(a1[2], fast_tanh((v.z - a2[2]) * a3[2]), a0[2]);
            o.w = __builtin_fmaf(a1[3], fast_tanh((v.w - a2[3]) * a3[3]), a0[3]);
            // out is never re-read: nontemporal store keeps z's L3 residency.
            __builtin_nontemporal_store(o,
                reinterpret_cast<f32x4*>(op + ((g - 1) * 4 + j) * STRIDE));
        }
        if (g < ITERS / 4) {
#pragma unroll
            for (int j = 0; j < 4; ++j) cur[j] = nxt[j];
        }
    }
#undef LDZ
}

extern "C" void kernel_launch(void* const* d_in, const int* in_sizes, int n_in,
                              void* d_out, int out_size, void* d_ws, size_t ws_size,
                              hipStream_t stream) {
    const float* z   = (const float*)d_in[0];
    const float* eta = (const float*)d_in[1];
    const int*   msk = (const int*)d_in[2];
    float*       out = (float*)d_out;

    dim3 grid(M_DIM * BLOCKS_PER_M);   // 2048 blocks, 8 per CU
    dim3 block(THREADS);
    invrt_kernel<<<grid, block, 0, stream>>>(z, eta, msk, out);
}

// Round 4
// 232.787 us; speedup vs baseline: 1.0363x; 1.0363x over previous
//
#include <hip/hip_runtime.h>

// InvRT: out[m,n,b,l] = -(e0 + e1*tanh((z - e2)*e3)), params from eta_fault[Mask[m,l]]
// z (8,64,512,128) f32. HBM-bound streaming op; floor ~41us @ 6.3 TB/s combined.
// R3: flat burst-8 load (all loads precede all uses, compile-time indices) so
// the compiler emits a descending vmcnt ladder instead of collapsing the
// pipeline (R0/R2 both degenerated to ~1 load in flight -> 84us latency-bound).
// 4096 blocks (2 generations) for tail refill.

#define M_DIM 8
#define L_DIM 128
#define PER_M 4194304        // N*B*L floats per m
#define BLOCKS_PER_M 512
#define THREADS 256
#define PER_BLOCK 8192       // PER_M / BLOCKS_PER_M floats
#define DEPTH 8              // float4s per thread, all in flight
#define STRIDE (THREADS * 4)

typedef float f32x4 __attribute__((ext_vector_type(4)));

__device__ __forceinline__ float fast_tanh(float x) {
    // tanh(x) = 1 - 2/(1 + exp2(x * 2*log2e)); saturates correctly at +-1.
    float t = __builtin_amdgcn_exp2f(x * 2.8853900817779268f);
    float r = __builtin_amdgcn_rcpf(1.0f + t);
    return __builtin_fmaf(-2.0f, r, 1.0f);
}

__global__ __launch_bounds__(THREADS, 1) void invrt_kernel(
    const float* __restrict__ z,
    const float* __restrict__ eta_fault,
    const int*  __restrict__ mask,
    float* __restrict__ out)
{
    const int tid   = threadIdx.x;
    const int bid   = blockIdx.x;
    const int m     = bid >> 9;        // 512 blocks per m
    const int chunk = bid & 511;

    // Thread owns l = l0..l0+3 for every iteration (iteration stride 1024 and
    // block base are multiples of L=128, so the l-phase is loop-invariant).
    const int l0 = (tid & 31) * 4;

    float a0[4], a1[4], a2[4], a3[4];
#pragma unroll
    for (int j = 0; j < 4; ++j) {
        const int row = mask[m * L_DIM + l0 + j];     // 0..18
        const f32x4 e = *reinterpret_cast<const f32x4*>(eta_fault + row * 4);
        a0[j] = -e.x;   // -e0
        a1[j] = -e.y;   // -e1
        a2[j] = e.z;    //  e2
        a3[j] = e.w;    //  e3
    }

    const long long base = (long long)m * PER_M + (long long)chunk * PER_BLOCK + tid * 4;
    const float* zp = z + base;
    float*       op = out + base;

    // Burst: issue ALL loads before ANY use. Flat array + compile-time
    // indices only -> stays in VGPRs, loads cluster, vmcnt ladder descends.
    f32x4 v[DEPTH];
#pragma unroll
    for (int j = 0; j < DEPTH; ++j)
        v[j] = *reinterpret_cast<const f32x4*>(zp + j * STRIDE);

#pragma unroll
    for (int j = 0; j < DEPTH; ++j) {
        f32x4 o;
        o.x = __builtin_fmaf(a1[0], fast_tanh((v[j].x - a2[0]) * a3[0]), a0[0]);
        o.y = __builtin_fmaf(a1[1], fast_tanh((v[j].y - a2[1]) * a3[1]), a0[1]);
        o.z = __builtin_fmaf(a1[2], fast_tanh((v[j].z - a2[2]) * a3[2]), a0[2]);
        o.w = __builtin_fmaf(a1[3], fast_tanh((v[j].w - a2[3]) * a3[3]), a0[3]);
        // out is never re-read: nontemporal store keeps z's L3 residency.
        __builtin_nontemporal_store(o, reinterpret_cast<f32x4*>(op + j * STRIDE));
    }
}

extern "C" void kernel_launch(void* const* d_in, const int* in_sizes, int n_in,
                              void* d_out, int out_size, void* d_ws, size_t ws_size,
                              hipStream_t stream) {
    const float* z   = (const float*)d_in[0];
    const float* eta = (const float*)d_in[1];
    const int*   msk = (const int*)d_in[2];
    float*       out = (float*)d_out;

    dim3 grid(M_DIM * BLOCKS_PER_M);   // 4096 blocks, 2 generations/CU
    dim3 block(THREADS);
    invrt_kernel<<<grid, block, 0, stream>>>(z, eta, msk, out);
}